// Round 5
// baseline (1963.097 us; speedup 1.0000x reference)
//
#include <hip/hip_runtime.h>

// VanillaRNN fused MFMA kernel for MI355X (gfx950) — dual-stream variant.
// B=256, T=512, D=128, H=256, O=128, fp32 in/out.
//
// 8 WGs x 512 threads; each WG owns 32 batch rows as TWO independent
// 16-row streams (waves 0-3 = stream A, waves 4-7 = stream B). The two
// streams interleave on the same SIMDs (2 waves/SIMD) so ds_read latency,
// MFMA dep chains and tanh of one stream hide under the other.
// Per stream/step: H_new[16,256] = tanh(xW_t + H @ W_hh^T) via
// mfma_f32_16x16x32_f16, W fragments VGPR-resident, h double-buffered in
// XOR-swizzled LDS. xW computed fused per 8-step chunk, kept f16 in regs.

typedef _Float16 f16;
typedef _Float16 f16x2 __attribute__((ext_vector_type(2)));
typedef _Float16 f16x4 __attribute__((ext_vector_type(4)));
typedef _Float16 f16x8 __attribute__((ext_vector_type(8)));
typedef float f32x4 __attribute__((ext_vector_type(4)));

#define NB 256
#define NT 512
#define ND 128
#define NH 256
#define NO 128
#define RS 16            // rows per stream
#define NSTR 2           // streams per WG
#define RWG (RS * NSTR)  // 32 rows per WG
#define TCH 8            // timesteps per chunk
#define NCH (NT / TCH)   // 64 chunks

__device__ __forceinline__ float fast_tanh(float z) {
  // tanh(z) = 1 - 2/(exp2(z*2*log2e) + 1)
  float e = __builtin_amdgcn_exp2f(z * 2.88539008177793f);
  float r = __builtin_amdgcn_rcpf(e + 1.0f);
  return __builtin_fmaf(-2.0f, r, 1.0f);
}

__device__ __forceinline__ f16x8 cvt8(const float* __restrict__ p) {
  f32x4 v0 = *(const f32x4*)p;
  f32x4 v1 = *(const f32x4*)(p + 4);
  f16x8 r;
  r[0] = (f16)v0.x; r[1] = (f16)v0.y; r[2] = (f16)v0.z; r[3] = (f16)v0.w;
  r[4] = (f16)v1.x; r[5] = (f16)v1.y; r[6] = (f16)v1.z; r[7] = (f16)v1.w;
  return r;
}

__global__ __launch_bounds__(512, 1)
void rnn_mfma2(const float* __restrict__ x,
               const float* __restrict__ Wx, const float* __restrict__ bx,
               const float* __restrict__ Wh, const float* __restrict__ bh,
               const float* __restrict__ Wp, const float* __restrict__ bp,
               float* __restrict__ out)
{
  const int wg  = blockIdx.x;    // 0..7
  const int tid = threadIdx.x;   // 0..511
  const int st  = tid >> 8;      // stream 0/1 (waves 0-3 / 4-7)
  const int wl  = (tid >> 6) & 3;// wave-within-stream: owns cols [wl*64, ..)
  const int l   = tid & 63;
  const int l15 = l & 15;
  const int g   = (l >> 4) & 3;  // K-subblock / C row group

  __shared__ alignas(16) f16 xlds[NSTR][TCH * RS][ND];  // 64 KB
  __shared__ alignas(16) f16 hbuf[NSTR][2][RS][NH];     // 32 KB

  // ---- W_hh B-fragments (64-col N-strip), VGPR-resident ----
  f16x8 fWh[4][8];   // 128 VGPRs
  #pragma unroll
  for (int ct = 0; ct < 4; ++ct) {
    const int j = wl * 64 + ct * 16 + l15;
    #pragma unroll
    for (int kt = 0; kt < 8; ++kt)
      fWh[ct][kt] = cvt8(Wh + (size_t)j * NH + kt * 32 + g * 8);
  }
  // ---- W_hx B-fragments ----
  f16x8 fWx[4][4];   // 64 VGPRs
  #pragma unroll
  for (int ct = 0; ct < 4; ++ct) {
    const int j = wl * 64 + ct * 16 + l15;
    #pragma unroll
    for (int kt = 0; kt < 4; ++kt)
      fWx[ct][kt] = cvt8(Wx + (size_t)j * ND + kt * 32 + g * 8);
  }
  float bias[4];
  #pragma unroll
  for (int ct = 0; ct < 4; ++ct) {
    const int j = wl * 64 + ct * 16 + l15;
    bias[ct] = bx[j] + bh[j];
  }

  // ---- h0 = 0 (both streams, both buffers' first) ----
  {
    unsigned* hz = (unsigned*)&hbuf[0][0][0][0];
    #pragma unroll
    for (int k = 0; k < (NSTR * 2 * RS * NH / 2) / 512; ++k)
      hz[tid + k * 512] = 0u;
  }
  __syncthreads();

  int cur = 0;
  f16x2 xwb[TCH][4][2];   // packed xW+bias for the chunk

  const int tis  = tid & 255;    // thread index within stream
  const int srow = tis >> 4;     // staging: 16 threads per batch row
  const int sq   = tis & 15;
  const int brow = wg * RWG + st * RS;            // first batch row of stream
  const float* xrow = x + (size_t)(brow + srow) * NT * ND;

  #pragma unroll 1
  for (int c = 0; c < NCH; ++c) {
    // ---- stage x[16 rows, 8t, 128d] -> LDS f16, swizzled A-layout ----
    const float* xc = xrow + (size_t)c * TCH * ND;
    #pragma unroll
    for (int jj = 0; jj < 16; ++jj) {
      const int f = (sq + jj * 16) * 4;   // float idx in 1024-float row chunk
      f32x4 v = *(const f32x4*)(xc + f);
      const int t = f >> 7;               // /ND
      const int d = f & (ND - 1);
      const int m = t * RS + srow;        // M index (t-major tiles of 16 rows)
      f16x4 h4;
      h4[0] = (f16)v.x; h4[1] = (f16)v.y; h4[2] = (f16)v.z; h4[3] = (f16)v.w;
      *(f16x4*)((char*)&xlds[st][m][0] + ((2 * d) ^ ((m & 7) << 4))) = h4;
    }
    __syncthreads();

    // ---- xW for the chunk via MFMA; keep (xW + bias) packed in regs ----
    #pragma unroll
    for (int t = 0; t < TCH; ++t) {
      f16x8 a[4];
      #pragma unroll
      for (int kt = 0; kt < 4; ++kt) {
        const int m = t * RS + l15;
        a[kt] = *(const f16x8*)((char*)&xlds[st][m][0] +
                 ((kt * 64 + g * 16) ^ ((m & 7) << 4)));
      }
      #pragma unroll
      for (int ct = 0; ct < 4; ++ct) {
        f32x4 ac = {bias[ct], bias[ct], bias[ct], bias[ct]};
        #pragma unroll
        for (int kt = 0; kt < 4; ++kt)
          ac = __builtin_amdgcn_mfma_f32_16x16x32_f16(a[kt], fWx[ct][kt], ac, 0, 0, 0);
        f16x2 p0; p0[0] = (f16)ac[0]; p0[1] = (f16)ac[1];
        f16x2 p1; p1[0] = (f16)ac[2]; p1[1] = (f16)ac[3];
        xwb[t][ct][0] = p0;
        xwb[t][ct][1] = p1;
      }
    }

    // ---- TCH serial recurrence steps ----
    #pragma unroll
    for (int s = 0; s < TCH; ++s) {
      f16x8 a[8];
      #pragma unroll
      for (int kt = 0; kt < 8; ++kt) {
        const int m = l15;
        a[kt] = *(const f16x8*)((char*)&hbuf[st][cur][m][0] +
                 ((kt * 64 + g * 16) ^ ((m & 7) << 4)));
      }
      const int nxt = cur ^ 1;
      #pragma unroll
      for (int ct = 0; ct < 4; ++ct) {
        f32x4 ac  = {(float)xwb[s][ct][0][0], (float)xwb[s][ct][0][1],
                     (float)xwb[s][ct][1][0], (float)xwb[s][ct][1][1]};
        f32x4 ac2 = {0.f, 0.f, 0.f, 0.f};
        #pragma unroll
        for (int kt = 0; kt < 4; ++kt) {   // two interleaved chains
          ac  = __builtin_amdgcn_mfma_f32_16x16x32_f16(a[2*kt],     fWh[ct][2*kt],     ac,  0, 0, 0);
          ac2 = __builtin_amdgcn_mfma_f32_16x16x32_f16(a[2*kt + 1], fWh[ct][2*kt + 1], ac2, 0, 0, 0);
        }
        #pragma unroll
        for (int rg = 0; rg < 4; ++rg) {
          const float th = fast_tanh(ac[rg] + ac2[rg]);
          const int row = g * 4 + rg;               // C layout: row=(l>>4)*4+reg
          const int col = wl * 64 + ct * 16 + l15;  //           col=lane&15
          *(f16*)((char*)&hbuf[st][nxt][row][0] +
                  ((2 * col) ^ ((row & 7) << 4))) = (f16)th;
        }
      }
      cur = nxt;
      __syncthreads();
    }
  }

  // ---- output projection: out[b,:] = h_T @ W_ph^T + b_ph ----
  f16x8 ah[8];
  #pragma unroll
  for (int kt = 0; kt < 8; ++kt) {
    const int m = l15;
    ah[kt] = *(const f16x8*)((char*)&hbuf[st][cur][m][0] +
             ((kt * 64 + g * 16) ^ ((m & 7) << 4)));
  }
  #pragma unroll
  for (int ct = 0; ct < 2; ++ct) {           // O=128 -> 32 cols per wave
    const int o = wl * 32 + ct * 16 + l15;
    f32x4 ac = {bp[o], bp[o], bp[o], bp[o]};
    #pragma unroll
    for (int kt = 0; kt < 8; ++kt) {
      f16x8 bfr = cvt8(Wp + (size_t)o * NH + kt * 32 + g * 8);
      ac = __builtin_amdgcn_mfma_f32_16x16x32_f16(ah[kt], bfr, ac, 0, 0, 0);
    }
    #pragma unroll
    for (int rg = 0; rg < 4; ++rg) {
      const int row = g * 4 + rg;
      out[(size_t)(brow + row) * NO + o] = ac[rg];
    }
  }
}

extern "C" void kernel_launch(void* const* d_in, const int* in_sizes, int n_in,
                              void* d_out, int out_size, void* d_ws, size_t ws_size,
                              hipStream_t stream) {
  const float* x   = (const float*)d_in[0];
  const float* whx = (const float*)d_in[1];
  const float* bhx = (const float*)d_in[2];
  const float* whh = (const float*)d_in[3];
  const float* bhh = (const float*)d_in[4];
  const float* wph = (const float*)d_in[5];
  const float* bph = (const float*)d_in[6];
  float* out = (float*)d_out;

  rnn_mfma2<<<dim3(NB / RWG), dim3(512), 0, stream>>>(x, whx, bhx, whh, bhh, wph, bph, out);
}

// Round 6
// 441.824 us; speedup vs baseline: 4.4432x; 4.4432x over previous
//
#include <hip/hip_runtime.h>

// VanillaRNN for MI355X (gfx950), two-kernel version.
// B=256, T=512, D=128, H=256, O=128, fp32 in/out.
//
// Kernel 1 (xw_gemm, 1024 WGs, all CUs): xW = x @ W_hx^T + bx + bh, stored
// f16 in d_ws in C-fragment order, so the scan reads it as 4 coalesced b64
// loads per lane per step.
// Kernel 2 (rnn_scan, 16 WGs): the serial scan. 4 waves per WG, each wave a
// 64-col N-strip; W_hh fragments VGPR-resident; h double-buffered in
// XOR-swizzled LDS; xw accumulator-init prefetched 2 steps ahead from d_ws.
// Fallback: if ws_size < 67MB, run the round-4 single-kernel version.

typedef _Float16 f16;
typedef _Float16 f16x2 __attribute__((ext_vector_type(2)));
typedef _Float16 f16x4 __attribute__((ext_vector_type(4)));
typedef _Float16 f16x8 __attribute__((ext_vector_type(8)));
typedef float f32x4 __attribute__((ext_vector_type(4)));

#define NB 256
#define NT 512
#define ND 128
#define NH 256
#define NO 128
#define R  16            // batch rows per WG (scan)
#define TCH 8            // timesteps per chunk (xw_gemm)
#define NCH (NT / TCH)   // 64 chunks
#define STEP_F16 4096    // f16 elements per (wg, step) xw block
#define WS_NEED ((size_t)(NB / R) * NT * STEP_F16 * 2)   // 67,108,864 bytes

__device__ __forceinline__ float fast_tanh(float z) {
  float e = __builtin_amdgcn_exp2f(z * 2.88539008177793f);
  float r = __builtin_amdgcn_rcpf(e + 1.0f);
  return __builtin_fmaf(-2.0f, r, 1.0f);
}

__device__ __forceinline__ f16x8 cvt8(const float* __restrict__ p) {
  f32x4 v0 = *(const f32x4*)p;
  f32x4 v1 = *(const f32x4*)(p + 4);
  f16x8 r;
  r[0] = (f16)v0.x; r[1] = (f16)v0.y; r[2] = (f16)v0.z; r[3] = (f16)v0.w;
  r[4] = (f16)v1.x; r[5] = (f16)v1.y; r[6] = (f16)v1.z; r[7] = (f16)v1.w;
  return r;
}

// ================= Kernel 1: xW projection into d_ws ====================
__global__ __launch_bounds__(256, 1)
void xw_gemm(const float* __restrict__ x,
             const float* __restrict__ Wx, const float* __restrict__ bx,
             const float* __restrict__ bh, f16* __restrict__ ws)
{
  const int wgb = blockIdx.x & 15;   // batch-row group
  const int c   = blockIdx.x >> 4;   // chunk
  const int tid = threadIdx.x;
  const int w   = tid >> 6;
  const int l15 = tid & 15;
  const int g   = (tid >> 4) & 3;

  __shared__ alignas(16) f16 xlds[TCH * R][ND];   // 32 KB, swizzled

  f16x8 fWx[4][4];
  float bias[4];
  #pragma unroll
  for (int ct = 0; ct < 4; ++ct) {
    const int j = w * 64 + ct * 16 + l15;
    #pragma unroll
    for (int kt = 0; kt < 4; ++kt)
      fWx[ct][kt] = cvt8(Wx + (size_t)j * ND + kt * 32 + g * 8);
    bias[ct] = bx[j] + bh[j];
  }

  const int srow = tid >> 4;
  const int sq   = tid & 15;
  const float* xc = x + ((size_t)(wgb * R + srow) * NT + (size_t)c * TCH) * ND;
  #pragma unroll
  for (int jj = 0; jj < 16; ++jj) {
    const int f = (sq + jj * 16) * 4;
    f32x4 v = *(const f32x4*)(xc + f);
    const int t = f >> 7;
    const int d = f & (ND - 1);
    const int m = t * R + srow;
    f16x4 h4;
    h4[0] = (f16)v.x; h4[1] = (f16)v.y; h4[2] = (f16)v.z; h4[3] = (f16)v.w;
    *(f16x4*)((char*)&xlds[m][0] + ((2 * d) ^ ((m & 7) << 4))) = h4;
  }
  __syncthreads();

  #pragma unroll
  for (int t = 0; t < TCH; ++t) {
    f16x8 a[4];
    #pragma unroll
    for (int kt = 0; kt < 4; ++kt) {
      const int m = t * R + l15;
      a[kt] = *(const f16x8*)((char*)&xlds[m][0] +
               ((kt * 64 + g * 16) ^ ((m & 7) << 4)));
    }
    f16* wsp = ws + ((size_t)(wgb * NT + c * TCH + t)) * STEP_F16
                  + w * 1024 + g * 64 + l15 * 4;
    #pragma unroll
    for (int ct = 0; ct < 4; ++ct) {
      f32x4 ac = {bias[ct], bias[ct], bias[ct], bias[ct]};
      #pragma unroll
      for (int kt = 0; kt < 4; ++kt)
        ac = __builtin_amdgcn_mfma_f32_16x16x32_f16(a[kt], fWx[ct][kt], ac, 0, 0, 0);
      f16x4 p;
      p[0] = (f16)ac[0]; p[1] = (f16)ac[1]; p[2] = (f16)ac[2]; p[3] = (f16)ac[3];
      *(f16x4*)(wsp + ct * 256) = p;
    }
  }
}

// ================= Kernel 2: the serial scan ====================
__global__ __launch_bounds__(256, 1)
void rnn_scan(const f16* __restrict__ ws,
              const float* __restrict__ Wh,
              const float* __restrict__ Wp, const float* __restrict__ bp,
              float* __restrict__ out)
{
  const int wg  = blockIdx.x;
  const int tid = threadIdx.x;
  const int w   = tid >> 6;
  const int l15 = tid & 15;
  const int g   = (tid >> 4) & 3;

  __shared__ alignas(16) f16 hbuf[2][R][NH];   // 16 KB, swizzled, dbuf

  f16x8 fWh[4][8];   // 128 VGPRs, resident
  #pragma unroll
  for (int ct = 0; ct < 4; ++ct) {
    const int j = w * 64 + ct * 16 + l15;
    #pragma unroll
    for (int kt = 0; kt < 8; ++kt)
      fWh[ct][kt] = cvt8(Wh + (size_t)j * NH + kt * 32 + g * 8);
  }

  {
    unsigned* hz = (unsigned*)&hbuf[0][0][0];
    #pragma unroll
    for (int k = 0; k < (R * NH / 2) / 256; ++k) hz[tid + k * 256] = 0u;
  }
  __syncthreads();

  const f16* wsg = ws + (size_t)wg * NT * STEP_F16 + w * 1024 + g * 64 + l15 * 4;

  f16x4 xA[4], xB[4];
  #pragma unroll
  for (int ct = 0; ct < 4; ++ct) xA[ct] = *(const f16x4*)(wsg + 0 * STEP_F16 + ct * 256);
  #pragma unroll
  for (int ct = 0; ct < 4; ++ct) xB[ct] = *(const f16x4*)(wsg + 1 * STEP_F16 + ct * 256);

  int cur = 0;

  auto step = [&](int tau, f16x4 (&xw)[4]) {
    f16x8 a[8];
    #pragma unroll
    for (int kt = 0; kt < 8; ++kt) {
      const int m = l15;
      a[kt] = *(const f16x8*)((char*)&hbuf[cur][m][0] +
               ((kt * 64 + g * 16) ^ ((m & 7) << 4)));
    }
    f32x4 ac[4], ac2[4];
    #pragma unroll
    for (int ct = 0; ct < 4; ++ct) {
      ac[ct][0] = (float)xw[ct][0]; ac[ct][1] = (float)xw[ct][1];
      ac[ct][2] = (float)xw[ct][2]; ac[ct][3] = (float)xw[ct][3];
      ac2[ct] = (f32x4){0.f, 0.f, 0.f, 0.f};
    }
    // prefetch xw for tau+2 (overwrites xw after its values were consumed)
    int pf = tau + 2; if (pf > NT - 1) pf = NT - 1;
    #pragma unroll
    for (int ct = 0; ct < 4; ++ct)
      xw[ct] = *(const f16x4*)(wsg + (size_t)pf * STEP_F16 + ct * 256);

    #pragma unroll
    for (int ct = 0; ct < 4; ++ct) {
      #pragma unroll
      for (int kt = 0; kt < 4; ++kt) {   // two interleaved K-chains
        ac[ct]  = __builtin_amdgcn_mfma_f32_16x16x32_f16(a[2*kt],     fWh[ct][2*kt],     ac[ct],  0, 0, 0);
        ac2[ct] = __builtin_amdgcn_mfma_f32_16x16x32_f16(a[2*kt + 1], fWh[ct][2*kt + 1], ac2[ct], 0, 0, 0);
      }
    }
    const int nxt = cur ^ 1;
    #pragma unroll
    for (int ct = 0; ct < 4; ++ct) {
      #pragma unroll
      for (int rg = 0; rg < 4; ++rg) {
        const float th = fast_tanh(ac[ct][rg] + ac2[ct][rg]);
        const int row = g * 4 + rg;
        const int col = w * 64 + ct * 16 + l15;
        *(f16*)((char*)&hbuf[nxt][row][0] +
                ((2 * col) ^ ((row & 7) << 4))) = (f16)th;
      }
    }
    cur = nxt;
    __syncthreads();
  };

  #pragma unroll 1
  for (int tau = 0; tau < NT; tau += 2) {
    step(tau, xA);
    step(tau + 1, xB);
  }

  // ---- output projection ----
  f16x8 ah[8];
  #pragma unroll
  for (int kt = 0; kt < 8; ++kt) {
    const int m = l15;
    ah[kt] = *(const f16x8*)((char*)&hbuf[cur][m][0] +
             ((kt * 64 + g * 16) ^ ((m & 7) << 4)));
  }
  #pragma unroll
  for (int ct = 0; ct < 2; ++ct) {
    const int o = w * 32 + ct * 16 + l15;
    f32x4 ac = {bp[o], bp[o], bp[o], bp[o]};
    #pragma unroll
    for (int kt = 0; kt < 8; ++kt) {
      f16x8 bfr = cvt8(Wp + (size_t)o * NH + kt * 32 + g * 8);
      ac = __builtin_amdgcn_mfma_f32_16x16x32_f16(ah[kt], bfr, ac, 0, 0, 0);
    }
    #pragma unroll
    for (int rg = 0; rg < 4; ++rg) {
      const int row = g * 4 + rg;
      out[(size_t)(wg * R + row) * NO + o] = ac[rg];
    }
  }
}

// ================= Fallback: round-4 single kernel ====================
__global__ __launch_bounds__(256, 1)
void rnn_mfma(const float* __restrict__ x,
              const float* __restrict__ Wx, const float* __restrict__ bx,
              const float* __restrict__ Wh, const float* __restrict__ bh,
              const float* __restrict__ Wp, const float* __restrict__ bp,
              float* __restrict__ out)
{
  const int wg  = blockIdx.x;
  const int tid = threadIdx.x;
  const int w   = tid >> 6;
  const int l15 = tid & 15;
  const int g   = (tid >> 4) & 3;

  __shared__ alignas(16) f16 xlds[TCH * R][ND];
  __shared__ alignas(16) f16 hbuf[2][R][NH];

  f16x8 fWh[4][8];
  #pragma unroll
  for (int ct = 0; ct < 4; ++ct) {
    const int j = w * 64 + ct * 16 + l15;
    #pragma unroll
    for (int kt = 0; kt < 8; ++kt)
      fWh[ct][kt] = cvt8(Wh + (size_t)j * NH + kt * 32 + g * 8);
  }
  f16x8 fWx[4][4];
  #pragma unroll
  for (int ct = 0; ct < 4; ++ct) {
    const int j = w * 64 + ct * 16 + l15;
    #pragma unroll
    for (int kt = 0; kt < 4; ++kt)
      fWx[ct][kt] = cvt8(Wx + (size_t)j * ND + kt * 32 + g * 8);
  }
  float bias[4];
  #pragma unroll
  for (int ct = 0; ct < 4; ++ct) {
    const int j = w * 64 + ct * 16 + l15;
    bias[ct] = bx[j] + bh[j];
  }
  {
    unsigned* hz = (unsigned*)&hbuf[0][0][0];
    #pragma unroll
    for (int k = 0; k < (R * NH / 2) / 256; ++k) hz[tid + k * 256] = 0u;
  }
  __syncthreads();

  int cur = 0;
  f16x2 xwb[TCH][4][2];
  const int srow = tid >> 4;
  const int sq   = tid & 15;
  const float* xrow = x + (size_t)(wg * R + srow) * NT * ND;

  #pragma unroll 1
  for (int c = 0; c < NCH; ++c) {
    const float* xc = xrow + (size_t)c * TCH * ND;
    #pragma unroll
    for (int jj = 0; jj < 16; ++jj) {
      const int f = (sq + jj * 16) * 4;
      f32x4 v = *(const f32x4*)(xc + f);
      const int t = f >> 7;
      const int d = f & (ND - 1);
      const int m = t * R + srow;
      f16x4 h4;
      h4[0] = (f16)v.x; h4[1] = (f16)v.y; h4[2] = (f16)v.z; h4[3] = (f16)v.w;
      *(f16x4*)((char*)&xlds[m][0] + ((2 * d) ^ ((m & 7) << 4))) = h4;
    }
    __syncthreads();

    #pragma unroll
    for (int t = 0; t < TCH; ++t) {
      f16x8 a[4];
      #pragma unroll
      for (int kt = 0; kt < 4; ++kt) {
        const int m = t * R + l15;
        a[kt] = *(const f16x8*)((char*)&xlds[m][0] +
                 ((kt * 64 + g * 16) ^ ((m & 7) << 4)));
      }
      #pragma unroll
      for (int ct = 0; ct < 4; ++ct) {
        f32x4 ac = {bias[ct], bias[ct], bias[ct], bias[ct]};
        #pragma unroll
        for (int kt = 0; kt < 4; ++kt)
          ac = __builtin_amdgcn_mfma_f32_16x16x32_f16(a[kt], fWx[ct][kt], ac, 0, 0, 0);
        f16x2 p0; p0[0] = (f16)ac[0]; p0[1] = (f16)ac[1];
        f16x2 p1; p1[0] = (f16)ac[2]; p1[1] = (f16)ac[3];
        xwb[t][ct][0] = p0;
        xwb[t][ct][1] = p1;
      }
    }

    #pragma unroll
    for (int s = 0; s < TCH; ++s) {
      f16x8 a[8];
      #pragma unroll
      for (int kt = 0; kt < 8; ++kt) {
        const int m = l15;
        a[kt] = *(const f16x8*)((char*)&hbuf[cur][m][0] +
                 ((kt * 64 + g * 16) ^ ((m & 7) << 4)));
      }
      const int nxt = cur ^ 1;
      #pragma unroll
      for (int ct = 0; ct < 4; ++ct) {
        f32x4 ac  = {(float)xwb[s][ct][0][0], (float)xwb[s][ct][0][1],
                     (float)xwb[s][ct][1][0], (float)xwb[s][ct][1][1]};
        f32x4 ac2 = {0.f, 0.f, 0.f, 0.f};
        #pragma unroll
        for (int kt = 0; kt < 4; ++kt) {
          ac  = __builtin_amdgcn_mfma_f32_16x16x32_f16(a[2*kt],     fWh[ct][2*kt],     ac,  0, 0, 0);
          ac2 = __builtin_amdgcn_mfma_f32_16x16x32_f16(a[2*kt + 1], fWh[ct][2*kt + 1], ac2, 0, 0, 0);
        }
        #pragma unroll
        for (int rg = 0; rg < 4; ++rg) {
          const float th = fast_tanh(ac[rg] + ac2[rg]);
          const int row = g * 4 + rg;
          const int col = w * 64 + ct * 16 + l15;
          *(f16*)((char*)&hbuf[nxt][row][0] +
                  ((2 * col) ^ ((row & 7) << 4))) = (f16)th;
        }
      }
      cur = nxt;
      __syncthreads();
    }
  }

  f16x8 ah[8];
  #pragma unroll
  for (int kt = 0; kt < 8; ++kt) {
    const int m = l15;
    ah[kt] = *(const f16x8*)((char*)&hbuf[cur][m][0] +
             ((kt * 64 + g * 16) ^ ((m & 7) << 4)));
  }
  #pragma unroll
  for (int ct = 0; ct < 2; ++ct) {
    const int o = w * 32 + ct * 16 + l15;
    f32x4 ac = {bp[o], bp[o], bp[o], bp[o]};
    #pragma unroll
    for (int kt = 0; kt < 8; ++kt) {
      f16x8 bfr = cvt8(Wp + (size_t)o * NH + kt * 32 + g * 8);
      ac = __builtin_amdgcn_mfma_f32_16x16x32_f16(ah[kt], bfr, ac, 0, 0, 0);
    }
    #pragma unroll
    for (int rg = 0; rg < 4; ++rg) {
      const int row = g * 4 + rg;
      out[(size_t)(wg * R + row) * NO + o] = ac[rg];
    }
  }
}

extern "C" void kernel_launch(void* const* d_in, const int* in_sizes, int n_in,
                              void* d_out, int out_size, void* d_ws, size_t ws_size,
                              hipStream_t stream) {
  const float* x   = (const float*)d_in[0];
  const float* whx = (const float*)d_in[1];
  const float* bhx = (const float*)d_in[2];
  const float* whh = (const float*)d_in[3];
  const float* bhh = (const float*)d_in[4];
  const float* wph = (const float*)d_in[5];
  const float* bph = (const float*)d_in[6];
  float* out = (float*)d_out;

  if (ws_size >= WS_NEED) {
    f16* ws = (f16*)d_ws;
    xw_gemm<<<dim3((NB / R) * NCH), dim3(256), 0, stream>>>(x, whx, bhx, bhh, ws);
    rnn_scan<<<dim3(NB / R), dim3(256), 0, stream>>>(ws, whh, wph, bph, out);
  } else {
    rnn_mfma<<<dim3(NB / R), dim3(256), 0, stream>>>(x, whx, bhx, whh, bhh, wph, bph, out);
  }
}

// Round 7
// 438.361 us; speedup vs baseline: 4.4783x; 1.0079x over previous
//
#include <hip/hip_runtime.h>

// VanillaRNN for MI355X (gfx950), two-kernel, swapped-operand version.
// B=256, T=512, D=128, H=256, O=128, fp32 in/out.
//
// Kernel 1 (xw_gemm, 1024 WGs): xW^T = W_hx · x^T + b, stored f16 in d_ws in
// scan C-fragment order (per lane: 4 consecutive units of one batch row).
// Kernel 2 (rnn_scan, 16 WGs x 4 waves): per step computes
// H_new^T = tanh(xW_t^T + W_hh · H^T) with mfma_f32_16x16x32_f16, A = W_hh
// VGPR-resident, B = h^T from XOR-swizzled LDS (ds_read_b128). The swapped
// C-layout makes each lane's 4 outputs contiguous -> single ds_write_b64
// per col-tile (4 writes/step vs 16 scalar b16), near-bank-uniform.
// Fallback single-kernel path if ws_size < 67 MB.

typedef _Float16 f16;
typedef _Float16 f16x2 __attribute__((ext_vector_type(2)));
typedef _Float16 f16x4 __attribute__((ext_vector_type(4)));
typedef _Float16 f16x8 __attribute__((ext_vector_type(8)));
typedef float f32x4 __attribute__((ext_vector_type(4)));

#define NB 256
#define NT 512
#define ND 128
#define NH 256
#define NO 128
#define R  16            // batch rows per WG (scan)
#define TCH 8            // timesteps per chunk (xw_gemm)
#define NCH (NT / TCH)   // 64 chunks
#define STEP_F16 4096    // f16 elements per (wg, step) xw block
#define WS_NEED ((size_t)(NB / R) * NT * STEP_F16 * 2)   // 67,108,864 bytes

__device__ __forceinline__ float fast_tanh(float z) {
  float e = __builtin_amdgcn_exp2f(z * 2.88539008177793f);
  float r = __builtin_amdgcn_rcpf(e + 1.0f);
  return __builtin_fmaf(-2.0f, r, 1.0f);
}

__device__ __forceinline__ f16x8 cvt8(const float* __restrict__ p) {
  f32x4 v0 = *(const f32x4*)p;
  f32x4 v1 = *(const f32x4*)(p + 4);
  f16x8 r;
  r[0] = (f16)v0.x; r[1] = (f16)v0.y; r[2] = (f16)v0.z; r[3] = (f16)v0.w;
  r[4] = (f16)v1.x; r[5] = (f16)v1.y; r[6] = (f16)v1.z; r[7] = (f16)v1.w;
  return r;
}

// ================= Kernel 1: xW^T projection into d_ws ====================
__global__ __launch_bounds__(256, 1)
void xw_gemm(const float* __restrict__ x,
             const float* __restrict__ Wx, const float* __restrict__ bx,
             const float* __restrict__ bh, f16* __restrict__ ws)
{
  const int wgb = blockIdx.x & 15;   // batch-row group
  const int c   = blockIdx.x >> 4;   // chunk
  const int tid = threadIdx.x;
  const int w   = tid >> 6;          // wave: unit strip [w*64, w*64+64)
  const int l15 = tid & 15;
  const int g   = (tid >> 4) & 3;

  __shared__ alignas(16) f16 xlds[TCH * R][ND];   // 32 KB, swizzled

  // A-operand: W_hx fragments (row = unit j, k = kt*32+g*8)
  f16x8 fWx[4][4];
  f32x4 bias4[4];
  #pragma unroll
  for (int ct = 0; ct < 4; ++ct) {
    const int j = w * 64 + ct * 16 + l15;
    #pragma unroll
    for (int kt = 0; kt < 4; ++kt)
      fWx[ct][kt] = cvt8(Wx + (size_t)j * ND + kt * 32 + g * 8);
    const int j0 = w * 64 + ct * 16 + g * 4;   // units for this lane's C rows
    #pragma unroll
    for (int rg = 0; rg < 4; ++rg)
      bias4[ct][rg] = bx[j0 + rg] + bh[j0 + rg];
  }

  const int srow = tid >> 4;
  const int sq   = tid & 15;
  const float* xc = x + ((size_t)(wgb * R + srow) * NT + (size_t)c * TCH) * ND;
  #pragma unroll
  for (int jj = 0; jj < 16; ++jj) {
    const int f = (sq + jj * 16) * 4;
    f32x4 v = *(const f32x4*)(xc + f);
    const int t = f >> 7;
    const int d = f & (ND - 1);
    const int m = t * R + srow;
    f16x4 h4;
    h4[0] = (f16)v.x; h4[1] = (f16)v.y; h4[2] = (f16)v.z; h4[3] = (f16)v.w;
    *(f16x4*)((char*)&xlds[m][0] + ((2 * d) ^ ((m & 7) << 4))) = h4;
  }
  __syncthreads();

  #pragma unroll
  for (int t = 0; t < TCH; ++t) {
    // B-operand: x^T fragments (col = batch l15 of time-tile t)
    f16x8 b[4];
    #pragma unroll
    for (int kt = 0; kt < 4; ++kt) {
      const int m = t * R + l15;
      b[kt] = *(const f16x8*)((char*)&xlds[m][0] +
               ((kt * 64 + g * 16) ^ ((m & 7) << 4)));
    }
    f16* wsp = ws + ((size_t)(wgb * NT + c * TCH + t)) * STEP_F16
                  + w * 1024 + g * 64 + l15 * 4;
    #pragma unroll
    for (int ct = 0; ct < 4; ++ct) {
      f32x4 ac = bias4[ct];
      #pragma unroll
      for (int kt = 0; kt < 4; ++kt)
        ac = __builtin_amdgcn_mfma_f32_16x16x32_f16(fWx[ct][kt], b[kt], ac, 0, 0, 0);
      f16x4 p;
      p[0] = (f16)ac[0]; p[1] = (f16)ac[1]; p[2] = (f16)ac[2]; p[3] = (f16)ac[3];
      *(f16x4*)(wsp + ct * 256) = p;   // units ct*16+g*4+[0..4), batch l15
    }
  }
}

// ================= Kernel 2: the serial scan ====================
__global__ __launch_bounds__(256, 1)
void rnn_scan(const f16* __restrict__ ws,
              const float* __restrict__ Wh,
              const float* __restrict__ Wp, const float* __restrict__ bp,
              float* __restrict__ out)
{
  const int wg  = blockIdx.x;
  const int tid = threadIdx.x;
  const int w   = tid >> 6;      // wave: unit strip [w*64, w*64+64)
  const int l15 = tid & 15;      // batch row owned by this lane (C col)
  const int g   = (tid >> 4) & 3;

  __shared__ alignas(16) f16 hbuf[2][R][NH];   // 16 KB: [batch][unit], swizzled

  // A-operand: W_hh fragments (row = unit j, k = kt*32+g*8), VGPR-resident
  f16x8 fWh[4][8];   // 128 VGPRs
  #pragma unroll
  for (int ct = 0; ct < 4; ++ct) {
    const int j = w * 64 + ct * 16 + l15;
    #pragma unroll
    for (int kt = 0; kt < 8; ++kt)
      fWh[ct][kt] = cvt8(Wh + (size_t)j * NH + kt * 32 + g * 8);
  }

  {
    unsigned* hz = (unsigned*)&hbuf[0][0][0];
    #pragma unroll
    for (int k = 0; k < (R * NH / 2) / 256; ++k) hz[tid + k * 256] = 0u;
  }
  __syncthreads();

  const f16* wsg = ws + (size_t)wg * NT * STEP_F16 + w * 1024 + g * 64 + l15 * 4;

  f16x4 xA[4], xB[4];
  #pragma unroll
  for (int ct = 0; ct < 4; ++ct) xA[ct] = *(const f16x4*)(wsg + 0 * STEP_F16 + ct * 256);
  #pragma unroll
  for (int ct = 0; ct < 4; ++ct) xB[ct] = *(const f16x4*)(wsg + 1 * STEP_F16 + ct * 256);

  int cur = 0;

  auto step = [&](int tau, f16x4 (&xw)[4]) {
    // B-operand: h^T fragments — lane reads its own batch row l15
    f16x8 b[8];
    #pragma unroll
    for (int kt = 0; kt < 8; ++kt)
      b[kt] = *(const f16x8*)((char*)&hbuf[cur][l15][0] +
               ((kt * 64 + g * 16) ^ ((l15 & 7) << 4)));

    f32x4 ac[4], ac2[4];
    #pragma unroll
    for (int ct = 0; ct < 4; ++ct) {
      ac[ct][0] = (float)xw[ct][0]; ac[ct][1] = (float)xw[ct][1];
      ac[ct][2] = (float)xw[ct][2]; ac[ct][3] = (float)xw[ct][3];
      ac2[ct] = (f32x4){0.f, 0.f, 0.f, 0.f};
    }
    // prefetch xw for tau+2
    int pf = tau + 2; if (pf > NT - 1) pf = NT - 1;
    #pragma unroll
    for (int ct = 0; ct < 4; ++ct)
      xw[ct] = *(const f16x4*)(wsg + (size_t)pf * STEP_F16 + ct * 256);

    #pragma unroll
    for (int ct = 0; ct < 4; ++ct) {
      #pragma unroll
      for (int kt = 0; kt < 4; ++kt) {   // two interleaved K-chains
        ac[ct]  = __builtin_amdgcn_mfma_f32_16x16x32_f16(fWh[ct][2*kt],     b[2*kt],     ac[ct],  0, 0, 0);
        ac2[ct] = __builtin_amdgcn_mfma_f32_16x16x32_f16(fWh[ct][2*kt + 1], b[2*kt + 1], ac2[ct], 0, 0, 0);
      }
    }
    const int nxt = cur ^ 1;
    #pragma unroll
    for (int ct = 0; ct < 4; ++ct) {
      // lane's 4 outputs = units w*64+ct*16+g*4+[0..4) of batch l15 -> 1 b64 write
      f16x4 h4;
      #pragma unroll
      for (int rg = 0; rg < 4; ++rg)
        h4[rg] = (f16)fast_tanh(ac[ct][rg] + ac2[ct][rg]);
      *(f16x4*)((char*)&hbuf[nxt][l15][0] +
                ((128 * w + 32 * ct + 8 * g) ^ ((l15 & 7) << 4))) = h4;
    }
    cur = nxt;
    __syncthreads();
  };

  #pragma unroll 1
  for (int tau = 0; tau < NT; tau += 2) {
    step(tau, xA);
    step(tau + 1, xB);
  }

  // ---- output projection: out^T = W_ph · h_T^T + b_ph ----
  f16x8 bh8[8];
  #pragma unroll
  for (int kt = 0; kt < 8; ++kt)
    bh8[kt] = *(const f16x8*)((char*)&hbuf[cur][l15][0] +
              ((kt * 64 + g * 16) ^ ((l15 & 7) << 4)));
  #pragma unroll
  for (int ct = 0; ct < 2; ++ct) {           // O=128 -> 32 units per wave
    const int j0 = w * 32 + ct * 16 + g * 4;
    f32x4 ac = {bp[j0], bp[j0 + 1], bp[j0 + 2], bp[j0 + 3]};
    #pragma unroll
    for (int kt = 0; kt < 8; ++kt) {
      f16x8 afr = cvt8(Wp + (size_t)(w * 32 + ct * 16 + l15) * NH + kt * 32 + g * 8);
      ac = __builtin_amdgcn_mfma_f32_16x16x32_f16(afr, bh8[kt], ac, 0, 0, 0);
    }
    #pragma unroll
    for (int rg = 0; rg < 4; ++rg)
      out[(size_t)(wg * R + l15) * NO + j0 + rg] = ac[rg];
  }
}

// ================= Fallback: round-4 single kernel ====================
__global__ __launch_bounds__(256, 1)
void rnn_mfma(const float* __restrict__ x,
              const float* __restrict__ Wx, const float* __restrict__ bx,
              const float* __restrict__ Wh, const float* __restrict__ bh,
              const float* __restrict__ Wp, const float* __restrict__ bp,
              float* __restrict__ out)
{
  const int wg  = blockIdx.x;
  const int tid = threadIdx.x;
  const int w   = tid >> 6;
  const int l15 = tid & 15;
  const int g   = (tid >> 4) & 3;

  __shared__ alignas(16) f16 xlds[TCH * R][ND];
  __shared__ alignas(16) f16 hbuf[2][R][NH];

  f16x8 fWh[4][8];
  #pragma unroll
  for (int ct = 0; ct < 4; ++ct) {
    const int j = w * 64 + ct * 16 + l15;
    #pragma unroll
    for (int kt = 0; kt < 8; ++kt)
      fWh[ct][kt] = cvt8(Wh + (size_t)j * NH + kt * 32 + g * 8);
  }
  f16x8 fWx[4][4];
  #pragma unroll
  for (int ct = 0; ct < 4; ++ct) {
    const int j = w * 64 + ct * 16 + l15;
    #pragma unroll
    for (int kt = 0; kt < 4; ++kt)
      fWx[ct][kt] = cvt8(Wx + (size_t)j * ND + kt * 32 + g * 8);
  }
  float bias[4];
  #pragma unroll
  for (int ct = 0; ct < 4; ++ct) {
    const int j = w * 64 + ct * 16 + l15;
    bias[ct] = bx[j] + bh[j];
  }
  {
    unsigned* hz = (unsigned*)&hbuf[0][0][0];
    #pragma unroll
    for (int k = 0; k < (R * NH / 2) / 256; ++k) hz[tid + k * 256] = 0u;
  }
  __syncthreads();

  int cur = 0;
  f16x2 xwb[TCH][4][2];
  const int srow = tid >> 4;
  const int sq   = tid & 15;
  const float* xrow = x + (size_t)(wg * R + srow) * NT * ND;

  #pragma unroll 1
  for (int c = 0; c < NCH; ++c) {
    const float* xc = xrow + (size_t)c * TCH * ND;
    #pragma unroll
    for (int jj = 0; jj < 16; ++jj) {
      const int f = (sq + jj * 16) * 4;
      f32x4 v = *(const f32x4*)(xc + f);
      const int t = f >> 7;
      const int d = f & (ND - 1);
      const int m = t * R + srow;
      f16x4 h4;
      h4[0] = (f16)v.x; h4[1] = (f16)v.y; h4[2] = (f16)v.z; h4[3] = (f16)v.w;
      *(f16x4*)((char*)&xlds[m][0] + ((2 * d) ^ ((m & 7) << 4))) = h4;
    }
    __syncthreads();

    #pragma unroll
    for (int t = 0; t < TCH; ++t) {
      f16x8 a[4];
      #pragma unroll
      for (int kt = 0; kt < 4; ++kt) {
        const int m = t * R + l15;
        a[kt] = *(const f16x8*)((char*)&xlds[m][0] +
                 ((kt * 64 + g * 16) ^ ((m & 7) << 4)));
      }
      #pragma unroll
      for (int ct = 0; ct < 4; ++ct) {
        f32x4 ac = {bias[ct], bias[ct], bias[ct], bias[ct]};
        #pragma unroll
        for (int kt = 0; kt < 4; ++kt)
          ac = __builtin_amdgcn_mfma_f32_16x16x32_f16(a[kt], fWx[ct][kt], ac, 0, 0, 0);
        f16x2 p0; p0[0] = (f16)ac[0]; p0[1] = (f16)ac[1];
        f16x2 p1; p1[0] = (f16)ac[2]; p1[1] = (f16)ac[3];
        xwb[t][ct][0] = p0;
        xwb[t][ct][1] = p1;
      }
    }

    #pragma unroll
    for (int s = 0; s < TCH; ++s) {
      f16x8 a[8];
      #pragma unroll
      for (int kt = 0; kt < 8; ++kt) {
        const int m = l15;
        a[kt] = *(const f16x8*)((char*)&hbuf[cur][m][0] +
                 ((kt * 64 + g * 16) ^ ((m & 7) << 4)));
      }
      const int nxt = cur ^ 1;
      #pragma unroll
      for (int ct = 0; ct < 4; ++ct) {
        f32x4 ac  = {(float)xwb[s][ct][0][0], (float)xwb[s][ct][0][1],
                     (float)xwb[s][ct][1][0], (float)xwb[s][ct][1][1]};
        f32x4 ac2 = {0.f, 0.f, 0.f, 0.f};
        #pragma unroll
        for (int kt = 0; kt < 4; ++kt) {
          ac  = __builtin_amdgcn_mfma_f32_16x16x32_f16(a[2*kt],     fWh[ct][2*kt],     ac,  0, 0, 0);
          ac2 = __builtin_amdgcn_mfma_f32_16x16x32_f16(a[2*kt + 1], fWh[ct][2*kt + 1], ac2, 0, 0, 0);
        }
        #pragma unroll
        for (int rg = 0; rg < 4; ++rg) {
          const float th = fast_tanh(ac[rg] + ac2[rg]);
          const int row = g * 4 + rg;
          const int col = w * 64 + ct * 16 + l15;
          *(f16*)((char*)&hbuf[nxt][row][0] +
                  ((2 * col) ^ ((row & 7) << 4))) = (f16)th;
        }
      }
      cur = nxt;
      __syncthreads();
    }
  }

  f16x8 ah[8];
  #pragma unroll
  for (int kt = 0; kt < 8; ++kt) {
    const int m = l15;
    ah[kt] = *(const f16x8*)((char*)&hbuf[cur][m][0] +
             ((kt * 64 + g * 16) ^ ((m & 7) << 4)));
  }
  #pragma unroll
  for (int ct = 0; ct < 2; ++ct) {
    const int o = w * 32 + ct * 16 + l15;
    f32x4 ac = {bp[o], bp[o], bp[o], bp[o]};
    #pragma unroll
    for (int kt = 0; kt < 8; ++kt) {
      f16x8 bfr = cvt8(Wp + (size_t)o * NH + kt * 32 + g * 8);
      ac = __builtin_amdgcn_mfma_f32_16x16x32_f16(ah[kt], bfr, ac, 0, 0, 0);
    }
    #pragma unroll
    for (int rg = 0; rg < 4; ++rg) {
      const int row = g * 4 + rg;
      out[(size_t)(wg * R + row) * NO + o] = ac[rg];
    }
  }
}

extern "C" void kernel_launch(void* const* d_in, const int* in_sizes, int n_in,
                              void* d_out, int out_size, void* d_ws, size_t ws_size,
                              hipStream_t stream) {
  const float* x   = (const float*)d_in[0];
  const float* whx = (const float*)d_in[1];
  const float* bhx = (const float*)d_in[2];
  const float* whh = (const float*)d_in[3];
  const float* bhh = (const float*)d_in[4];
  const float* wph = (const float*)d_in[5];
  const float* bph = (const float*)d_in[6];
  float* out = (float*)d_out;

  if (ws_size >= WS_NEED) {
    f16* ws = (f16*)d_ws;
    xw_gemm<<<dim3((NB / R) * NCH), dim3(256), 0, stream>>>(x, whx, bhx, bhh, ws);
    rnn_scan<<<dim3(NB / R), dim3(256), 0, stream>>>(ws, whh, wph, bph, out);
  } else {
    rnn_mfma<<<dim3(NB / R), dim3(256), 0, stream>>>(x, whx, bhx, whh, bhh, wph, bph, out);
  }
}